// Round 3
// baseline (25946.793 us; speedup 1.0000x reference)
//
#include <hip/hip_runtime.h>
#include <math.h>

#define EOS_ID 2
#define START_ID 1
#define NEGV (-1e9f)
#define NBLK 256

__device__ __forceinline__ float sigmoidf_(float x) { return 1.f / (1.f + expf(-x)); }

// merge two desc-sorted (val, col) top-4 lists; tie: lower col wins. Result into l*.
__device__ __forceinline__ void merge4_(float lv[4], int lc[4],
                                        const float rv[4], const int rc[4]) {
    float ov[4]; int oc[4];
    int ai = 0, bi = 0;
    #pragma unroll
    for (int o = 0; o < 4; o++) {
        const float avv = (ai == 0) ? lv[0] : (ai == 1) ? lv[1] : (ai == 2) ? lv[2] : lv[3];
        const int   acc = (ai == 0) ? lc[0] : (ai == 1) ? lc[1] : (ai == 2) ? lc[2] : lc[3];
        const float bvv = (bi == 0) ? rv[0] : (bi == 1) ? rv[1] : (bi == 2) ? rv[2] : rv[3];
        const int   bcc = (bi == 0) ? rc[0] : (bi == 1) ? rc[1] : (bi == 2) ? rc[2] : rc[3];
        const bool ta = (avv > bvv) || (avv == bvv && acc < bcc);
        ov[o] = ta ? avv : bvv;
        oc[o] = ta ? acc : bcc;
        if (ta) ai++; else bi++;
    }
    #pragma unroll
    for (int o = 0; o < 4; o++) { lv[o] = ov[o]; lc[o] = oc[o]; }
}

__device__ __forceinline__ void lse_combine_(float& m, float& s, float m2, float s2) {
    const float M = fmaxf(m, m2);
    s = s * expf(m - M) + s2 * expf(m2 - M);
    m = M;
}

// sense-reversing grid barrier; all NBLK blocks co-resident (LDS/VGPR allow >=4 blk/CU)
__device__ __forceinline__ void gbar(int* cnt, int* sense, int* ls) {
    __syncthreads();
    if (threadIdx.x == 0) {
        const int s = 1 - *ls;
        *ls = s;
        __threadfence();
        if (__hip_atomic_fetch_add(cnt, 1, __ATOMIC_ACQ_REL, __HIP_MEMORY_SCOPE_AGENT)
            == NBLK - 1) {
            __hip_atomic_store(cnt, 0, __ATOMIC_RELAXED, __HIP_MEMORY_SCOPE_AGENT);
            __hip_atomic_store(sense, s, __ATOMIC_RELEASE, __HIP_MEMORY_SCOPE_AGENT);
        } else {
            while (__hip_atomic_load(sense, __ATOMIC_ACQUIRE,
                                     __HIP_MEMORY_SCOPE_AGENT) != s) {
                __builtin_amdgcn_s_sleep(2);
            }
        }
        __threadfence();
    }
    __syncthreads();
}

// ---------------------------------------------------------------------------
// Generic fp32 GEMM: C[M,N] = A[M,K] @ B[K,N] (+bias)
// AMODE 0: plain A. AMODE 2: encoder embedding gather (row r=s*32+b, tok[b*128+s])
// TRANS 1: store C transposed as keysT[b][n][s] with r = b*128+s  (no bias)
// ---------------------------------------------------------------------------
template<int BM, int BN, int BK, int AMODE, int TRANS>
__global__ void __launch_bounds__(256) gemm_k(
    const float* __restrict__ A, const float* __restrict__ B,
    const float* __restrict__ bias, float* __restrict__ C,
    int M, int N, int K, const int* __restrict__ tokp)
{
    static_assert(BN == 64, "");
    constexpr int TM = BM / 16, TN = BN / 16;
    __shared__ __align__(16) float As[BK][BM];
    __shared__ __align__(16) float Bs[BK][BN];
    const int tid = threadIdx.x;
    const int n0 = blockIdx.x * BN, m0 = blockIdx.y * BM;
    const int tx = tid & 15, ty = tid >> 4;
    (void)M;

    float acc[TM][TN];
    #pragma unroll
    for (int i = 0; i < TM; i++)
        #pragma unroll
        for (int j = 0; j < TN; j++) acc[i][j] = 0.f;

    constexpr int A4 = BM * BK / 4;

    for (int k0 = 0; k0 < K; k0 += BK) {
        if (A4 >= 256 || tid < A4) {
            const int am  = tid / (BK / 4);
            const int ak4 = tid % (BK / 4);
            const int kg  = k0 + ak4 * 4;
            float4 av;
            if (AMODE == 0) {
                av = *reinterpret_cast<const float4*>(A + (size_t)(m0 + am) * K + kg);
            } else {  // AMODE 2
                const int r = m0 + am;
                const int s = r >> 5, b = r & 31;
                av = *reinterpret_cast<const float4*>(
                    A + (size_t)tokp[b * 128 + s] * 512 + kg);
            }
            As[ak4 * 4 + 0][am] = av.x;
            As[ak4 * 4 + 1][am] = av.y;
            As[ak4 * 4 + 2][am] = av.z;
            As[ak4 * 4 + 3][am] = av.w;
        }
        {
            const int bk = tid >> 4, bn4 = tid & 15;
            *reinterpret_cast<float4*>(&Bs[bk][bn4 * 4]) =
                *reinterpret_cast<const float4*>(B + (size_t)(k0 + bk) * N + n0 + bn4 * 4);
        }
        __syncthreads();
        #pragma unroll
        for (int kk = 0; kk < BK; kk++) {
            float af[TM], bf[TN];
            if constexpr (TM == 4) {
                const float4 t4 = *reinterpret_cast<const float4*>(&As[kk][ty * TM]);
                af[0] = t4.x; af[1] = t4.y; af[2] = t4.z; af[3] = t4.w;
            } else if constexpr (TM == 2) {
                const float2 t2 = *reinterpret_cast<const float2*>(&As[kk][ty * TM]);
                af[0] = t2.x; af[1] = t2.y;
            } else {
                af[0] = As[kk][ty];
            }
            const float4 b4 = *reinterpret_cast<const float4*>(&Bs[kk][tx * TN]);
            bf[0] = b4.x; bf[1] = b4.y; bf[2] = b4.z; bf[3] = b4.w;
            #pragma unroll
            for (int i = 0; i < TM; i++)
                #pragma unroll
                for (int j = 0; j < TN; j++) acc[i][j] += af[i] * bf[j];
        }
        __syncthreads();
    }

    if constexpr (TRANS) {
        #pragma unroll
        for (int i = 0; i < TM; i++) {
            const int r = m0 + ty * TM + i;
            const int b = r >> 7, s = r & 127;
            #pragma unroll
            for (int j = 0; j < TN; j++)
                C[((size_t)b * 512 + (n0 + tx * TN + j)) * 128 + s] = acc[i][j];
        }
    } else {
        float bv[TN];
        #pragma unroll
        for (int j = 0; j < TN; j++) bv[j] = bias ? bias[n0 + tx * TN + j] : 0.f;
        #pragma unroll
        for (int i = 0; i < TM; i++) {
            float4 o;
            o.x = acc[i][0] + bv[0]; o.y = acc[i][1] + bv[1];
            o.z = acc[i][2] + bv[2]; o.w = acc[i][3] + bv[3];
            *reinterpret_cast<float4*>(C + (size_t)(m0 + ty * TM + i) * N + n0 + tx * TN) = o;
        }
    }
}

// ---------------------------------------------------------------------------
// prep: pack encoder weights (col' = j*4+g), pack decoder [W_dec;U_dec] the
// same way, pack biases, zero the grid-barrier counters.
// ---------------------------------------------------------------------------
__global__ void __launch_bounds__(256) prep_k(
    const float* __restrict__ W_enc, const float* __restrict__ U_enc,
    const float* __restrict__ b_enc, const float* __restrict__ W_dec,
    const float* __restrict__ U_dec, const float* __restrict__ b_dec,
    float* __restrict__ Wpe, float* __restrict__ bpe, float* __restrict__ Upe,
    float* __restrict__ Bpd, float* __restrict__ bpd,
    int* __restrict__ cnt, int* __restrict__ sense)
{
    const long idx = (long)blockIdx.x * 256 + threadIdx.x;
    if (idx < 512l * 2048) {
        const int k = idx >> 11, cp = idx & 2047;
        const int j = cp >> 2, g = cp & 3;
        const int sc = g * 512 + j;
        Wpe[idx] = W_enc[(size_t)k * 2048 + sc];
        Upe[idx] = U_enc[(size_t)k * 2048 + sc];
        if (k == 0) bpe[cp] = b_enc[sc];
    }
    const long idx2 = idx - 512l * 2048;
    if (idx2 >= 0 && idx2 < 1536l * 2048) {
        const int k = idx2 >> 11, cp = idx2 & 2047;
        const int j = cp >> 2, g = cp & 3;
        const int sc = g * 512 + j;
        Bpd[idx2] = (k < 1024) ? W_dec[(size_t)k * 2048 + sc]
                               : U_dec[(size_t)(k - 1024) * 2048 + sc];
        if (idx2 < 2048) bpd[idx2] = b_dec[sc];
    }
    if (idx == 0) { *cnt = 0; *sense = 0; }
}

// ---------------------------------------------------------------------------
// Persistent encoder: 32 blocks (one per batch row) x 512 threads (one per
// hidden unit; packed gates). c in registers, h ping-pong in LDS, 1 barrier/step.
// ---------------------------------------------------------------------------
__global__ void __launch_bounds__(512) encoder_k(
    const float* __restrict__ Xzp,   // [128][32][2048] packed z = x@W+b
    const float* __restrict__ Upe,   // [512][2048] packed U_enc
    float* __restrict__ enc_out,     // [32][128][512]
    float* __restrict__ enc_c)       // [32][512]
{
    __shared__ float hb[2][512];
    const int b = blockIdx.x, tid = threadIdx.x;
    float c = 0.f;
    hb[1][tid] = 0.f;
    __syncthreads();
    for (int t = 0; t < 128; t++) {
        const int cur = t & 1, prv = cur ^ 1;
        float4 acc = *reinterpret_cast<const float4*>(
            Xzp + ((size_t)t * 32 + b) * 2048 + tid * 4);
        const float* up = Upe + tid * 4;
        #pragma unroll 8
        for (int k = 0; k < 512; k++) {
            const float hk = hb[prv][k];
            const float4 u = *reinterpret_cast<const float4*>(up + (size_t)k * 2048);
            acc.x += hk * u.x; acc.y += hk * u.y;
            acc.z += hk * u.z; acc.w += hk * u.w;
        }
        const float iv = sigmoidf_(acc.x), fv = sigmoidf_(acc.y);
        const float gv = tanhf(acc.z),     ov = sigmoidf_(acc.w);
        c = fv * c + iv * gv;
        const float h = ov * tanhf(c);
        hb[cur][tid] = h;
        enc_out[((size_t)b * 128 + t) * 512 + tid] = h;
        __syncthreads();
    }
    enc_c[(size_t)b * 512 + tid] = c;
}

// ---------------------------------------------------------------------------
// Decoder megakernel: 256 blocks x 256 threads, 48 steps with 4 grid barriers
// per step. Phases: zgemm+gates -> attention+attn-proj -> logits+top4 partials
// -> merge/beam-update. Parent indirection + ping-pong state (no gather copies).
// ---------------------------------------------------------------------------
__global__ void __launch_bounds__(256) mega_k(
    const float* __restrict__ dec_emb, const float* __restrict__ Bpd,
    const float* __restrict__ bpd, const float* __restrict__ keysT,
    const float* __restrict__ enc_out, const float* __restrict__ enc_c,
    const float* __restrict__ W_attn, const float* __restrict__ W_out,
    const float* __restrict__ b_out,
    float* __restrict__ AcatA, float* __restrict__ AcatB,
    float* __restrict__ cAq, float* __restrict__ cBq,
    float* __restrict__ atA, float* __restrict__ atB,
    float* __restrict__ pmax, float* __restrict__ psum,
    float* __restrict__ pval, int* __restrict__ pcol,
    float* __restrict__ cum, int* __restrict__ fin, int* __restrict__ tok,
    int* __restrict__ par, int* __restrict__ parents, int* __restrict__ toks,
    int* __restrict__ out, int* cnt, int* sense)
{
    const int bid = blockIdx.x, tid = threadIdx.x;
    __shared__ int ls;
    __shared__ __align__(16) float zAs[16][16];
    __shared__ __align__(16) float zBs[16][64];
    __shared__ __align__(16) float co[512];
    __shared__ __align__(16) float cx[512];
    __shared__ float sc[128], scp[2][128], red[128];
    __shared__ __align__(16) float lAs[16][128];
    __shared__ __align__(16) float lBs[16][64];
    __shared__ float mm[256], ms[256];
    __shared__ float mv[256][4];
    __shared__ int   mc[256][4];
    __shared__ float rowv[4][4], rowlse[4];
    __shared__ int   rowc[4][4];

    if (tid == 0) ls = 0;

    // ---- init phase: beam state into "prev" bank (B) ----
    if (bid < 128) {
        const int r = bid, b = r >> 2;
        for (int j = tid; j < 512; j += 256) {
            AcatB[(size_t)r * 1024 + j] = enc_out[((size_t)b * 128 + 127) * 512 + j];
            atB[(size_t)r * 512 + j] = 0.f;
            cBq[(size_t)r * 512 + j] = enc_c[(size_t)b * 512 + j];
        }
        if (tid == 0) {
            cum[r] = (r & 3) ? NEGV : 0.f;
            fin[r] = 0; tok[r] = START_ID; par[r] = r & 3;
        }
    }
    gbar(cnt, sense, &ls);

    for (int t = 0; t < 48; t++) {
        float* AcatC = (t & 1) ? AcatB : AcatA;
        float* AcatP = (t & 1) ? AcatA : AcatB;
        float* cC = (t & 1) ? cBq : cAq;
        float* cP = (t & 1) ? cAq : cBq;
        float* atC = (t & 1) ? atB : atA;
        float* atP = (t & 1) ? atA : atB;

        // ---- phase 1: z GEMM + LSTM gates (grid (32 n0, 8 m0)) ----
        {
            const int n0 = (bid & 31) * 64, m0 = (bid >> 5) * 16;
            const int tx = tid & 15, ty = tid >> 4;
            float acc[4] = {0.f, 0.f, 0.f, 0.f};
            for (int k0 = 0; k0 < 1536; k0 += 16) {
                if (tid < 64) {
                    const int am = tid >> 2, ak4 = tid & 3;
                    const int kg = k0 + ak4 * 4;
                    const int r = m0 + am;
                    const int sr = (r & ~3) + par[r];
                    float4 av;
                    if (kg < 512)
                        av = *reinterpret_cast<const float4*>(
                            dec_emb + (size_t)tok[r] * 512 + kg);
                    else if (kg < 1024)
                        av = *reinterpret_cast<const float4*>(
                            atP + (size_t)sr * 512 + (kg - 512));
                    else
                        av = *reinterpret_cast<const float4*>(
                            AcatP + (size_t)sr * 1024 + (kg - 1024));
                    zAs[ak4 * 4 + 0][am] = av.x;
                    zAs[ak4 * 4 + 1][am] = av.y;
                    zAs[ak4 * 4 + 2][am] = av.z;
                    zAs[ak4 * 4 + 3][am] = av.w;
                }
                {
                    const int bk = tid >> 4, bn4 = tid & 15;
                    *reinterpret_cast<float4*>(&zBs[bk][bn4 * 4]) =
                        *reinterpret_cast<const float4*>(
                            Bpd + (size_t)(k0 + bk) * 2048 + n0 + bn4 * 4);
                }
                __syncthreads();
                #pragma unroll
                for (int kk = 0; kk < 16; kk++) {
                    const float a = zAs[kk][ty];
                    const float4 b4 = *reinterpret_cast<const float4*>(&zBs[kk][tx * 4]);
                    acc[0] += a * b4.x; acc[1] += a * b4.y;
                    acc[2] += a * b4.z; acc[3] += a * b4.w;
                }
                __syncthreads();
            }
            const int r = m0 + ty;
            const int sr = (r & ~3) + par[r];
            const int j = (n0 >> 2) + tx;
            const float iv = sigmoidf_(acc[0] + bpd[n0 + tx * 4 + 0]);
            const float fv = sigmoidf_(acc[1] + bpd[n0 + tx * 4 + 1]);
            const float gv = tanhf   (acc[2] + bpd[n0 + tx * 4 + 2]);
            const float ov = sigmoidf_(acc[3] + bpd[n0 + tx * 4 + 3]);
            const float cv = fv * cP[(size_t)sr * 512 + j] + iv * gv;
            cC[(size_t)r * 512 + j] = cv;
            AcatC[(size_t)r * 1024 + j] = ov * tanhf(cv);
        }
        gbar(cnt, sense, &ls);

        // ---- phase 2: attention + attn projection (2 blocks per row) ----
        {
            const int r = bid >> 1, half = bid & 1, b = r >> 2;
            if (tid < 128)
                *reinterpret_cast<float4*>(co + tid * 4) =
                    *reinterpret_cast<const float4*>(AcatC + (size_t)r * 1024 + tid * 4);
            __syncthreads();
            {
                const int h2 = tid >> 7, s = tid & 127;
                const float* kp = keysT + ((size_t)b * 512 + h2 * 256) * 128 + s;
                float a = 0.f;
                #pragma unroll 8
                for (int kk = 0; kk < 256; kk++)
                    a += co[h2 * 256 + kk] * kp[(size_t)kk * 128];
                scp[h2][s] = a;
            }
            __syncthreads();
            if (tid < 128) sc[tid] = scp[0][tid] + scp[1][tid];
            __syncthreads();
            if (tid < 64) red[tid] = fmaxf(sc[tid], sc[tid + 64]);
            __syncthreads();
            for (int st = 32; st >= 1; st >>= 1) {
                if (tid < st) red[tid] = fmaxf(red[tid], red[tid + st]);
                __syncthreads();
            }
            const float m = red[0];
            __syncthreads();
            if (tid < 128) sc[tid] = expf(sc[tid] - m);
            __syncthreads();
            if (tid < 64) red[tid] = sc[tid] + sc[tid + 64];
            __syncthreads();
            for (int st = 32; st >= 1; st >>= 1) {
                if (tid < st) red[tid] += red[tid + st];
                __syncthreads();
            }
            const float S = red[0];
            __syncthreads();
            if (tid < 128) sc[tid] = sc[tid] / S;
            __syncthreads();
            {
                float a0 = 0.f, a1 = 0.f;
                for (int s = 0; s < 128; s++) {
                    const float w = sc[s];
                    const float* vr = enc_out + ((size_t)b * 128 + s) * 512;
                    a0 += w * vr[tid];
                    a1 += w * vr[tid + 256];
                }
                cx[tid] = a0; cx[tid + 256] = a1;
            }
            __syncthreads();
            {
                const int j = half * 256 + tid;
                float a = 0.f;
                #pragma unroll 8
                for (int k = 0; k < 512; k++) a += co[k] * W_attn[(size_t)k * 512 + j];
                #pragma unroll 8
                for (int k = 0; k < 512; k++)
                    a += cx[k] * W_attn[(size_t)(512 + k) * 512 + j];
                atC[(size_t)r * 512 + j] = a;
            }
        }
        gbar(cnt, sense, &ls);

        // ---- phase 3: logits GEMM + per-tile top-4/lse partials (2 tiles/blk) ----
        for (int pass = 0; pass < 2; pass++) {
            const int tile = (pass == 0) ? bid : bid + 256;
            if (tile < 500) {
                const int n0 = tile * 64;
                const int tx = tid & 15, ty = tid >> 4;
                float acc[8][4];
                #pragma unroll
                for (int i = 0; i < 8; i++)
                    #pragma unroll
                    for (int j = 0; j < 4; j++) acc[i][j] = 0.f;

                for (int k0 = 0; k0 < 512; k0 += 16) {
                    #pragma unroll
                    for (int p = 0; p < 2; p++) {
                        const int idx = p * 256 + tid;
                        const int am = idx >> 2, ak4 = idx & 3;
                        const float4 av = *reinterpret_cast<const float4*>(
                            atC + (size_t)am * 512 + k0 + ak4 * 4);
                        lAs[ak4 * 4 + 0][am] = av.x;
                        lAs[ak4 * 4 + 1][am] = av.y;
                        lAs[ak4 * 4 + 2][am] = av.z;
                        lAs[ak4 * 4 + 3][am] = av.w;
                    }
                    {
                        const int bk = tid >> 4, bn4 = tid & 15;
                        *reinterpret_cast<float4*>(&lBs[bk][bn4 * 4]) =
                            *reinterpret_cast<const float4*>(
                                W_out + (size_t)(k0 + bk) * 32000 + n0 + bn4 * 4);
                    }
                    __syncthreads();
                    #pragma unroll
                    for (int kk = 0; kk < 16; kk++) {
                        float af[8];
                        const float4 t0 = *reinterpret_cast<const float4*>(&lAs[kk][ty * 8]);
                        const float4 t1 = *reinterpret_cast<const float4*>(&lAs[kk][ty * 8 + 4]);
                        af[0] = t0.x; af[1] = t0.y; af[2] = t0.z; af[3] = t0.w;
                        af[4] = t1.x; af[5] = t1.y; af[6] = t1.z; af[7] = t1.w;
                        const float4 b4 = *reinterpret_cast<const float4*>(&lBs[kk][tx * 4]);
                        #pragma unroll
                        for (int i = 0; i < 8; i++) {
                            acc[i][0] += af[i] * b4.x; acc[i][1] += af[i] * b4.y;
                            acc[i][2] += af[i] * b4.z; acc[i][3] += af[i] * b4.w;
                        }
                    }
                    __syncthreads();
                }

                float bv[4];
                #pragma unroll
                for (int j = 0; j < 4; j++) bv[j] = b_out[n0 + tx * 4 + j];

                #pragma unroll
                for (int i = 0; i < 8; i++) {
                    const int r = ty * 8 + i;
                    float lv[4]; int lc[4];
                    #pragma unroll
                    for (int j = 0; j < 4; j++) {
                        lv[j] = acc[i][j] + bv[j];
                        lc[j] = n0 + tx * 4 + j;
                    }
                    float rm = fmaxf(fmaxf(lv[0], lv[1]), fmaxf(lv[2], lv[3]));
                    #pragma unroll
                    for (int d = 1; d <= 8; d <<= 1) rm = fmaxf(rm, __shfl_xor(rm, d));
                    float s4 = expf(lv[0] - rm) + expf(lv[1] - rm) +
                               expf(lv[2] - rm) + expf(lv[3] - rm);
                    #pragma unroll
                    for (int d = 1; d <= 8; d <<= 1) s4 += __shfl_xor(s4, d);
                    #pragma unroll
                    for (int p = 0; p < 3; p++)
                        #pragma unroll
                        for (int q = 0; q < 3 - p; q++)
                            if (lv[q + 1] > lv[q]) {
                                const float tv = lv[q]; lv[q] = lv[q + 1]; lv[q + 1] = tv;
                                const int tc = lc[q]; lc[q] = lc[q + 1]; lc[q + 1] = tc;
                            }
                    #pragma unroll
                    for (int d = 1; d <= 8; d <<= 1) {
                        float rv[4]; int rc[4];
                        #pragma unroll
                        for (int j = 0; j < 4; j++) {
                            rv[j] = __shfl_xor(lv[j], d);
                            rc[j] = __shfl_xor(lc[j], d);
                        }
                        merge4_(lv, lc, rv, rc);
                    }
                    if (tx == 0) {
                        pmax[r * 512 + tile] = rm;
                        psum[r * 512 + tile] = s4;
                        #pragma unroll
                        for (int j = 0; j < 4; j++) {
                            pval[(r * 4 + j) * 512 + tile] = lv[j];
                            pcol[(r * 4 + j) * 512 + tile] = lc[j];
                        }
                    }
                }
            }
        }
        gbar(cnt, sense, &ls);

        // ---- phase 4: merge partials + beam update (blocks 0..31, b = bid) ----
        if (bid < 32) {
            const int b = bid;
            const int j4 = tid >> 6, lt = tid & 63;
            const int r = b * 4 + j4;
            float m = -INFINITY, s = 0.f;
            float lv[4] = {-INFINITY, -INFINITY, -INFINITY, -INFINITY};
            int lc[4] = {0x7FFFFFFF, 0x7FFFFFFF, 0x7FFFFFFF, 0x7FFFFFFF};
            for (int tt = lt; tt < 500; tt += 64) {
                lse_combine_(m, s, pmax[r * 512 + tt], psum[r * 512 + tt]);
                float rv[4]; int rc[4];
                #pragma unroll
                for (int j = 0; j < 4; j++) {
                    rv[j] = pval[(r * 4 + j) * 512 + tt];
                    rc[j] = pcol[(r * 4 + j) * 512 + tt];
                }
                merge4_(lv, lc, rv, rc);
            }
            mm[tid] = m; ms[tid] = s;
            #pragma unroll
            for (int j = 0; j < 4; j++) { mv[tid][j] = lv[j]; mc[tid][j] = lc[j]; }
            __syncthreads();
            for (int st = 32; st >= 1; st >>= 1) {
                if (lt < st) {
                    lse_combine_(m, s, mm[tid + st], ms[tid + st]);
                    mm[tid] = m; ms[tid] = s;
                    float rv[4]; int rc[4];
                    #pragma unroll
                    for (int j = 0; j < 4; j++) {
                        rv[j] = mv[tid + st][j]; rc[j] = mc[tid + st][j];
                    }
                    merge4_(lv, lc, rv, rc);
                    #pragma unroll
                    for (int j = 0; j < 4; j++) { mv[tid][j] = lv[j]; mc[tid][j] = lc[j]; }
                }
                __syncthreads();
            }
            if (lt == 0) {
                rowlse[j4] = m + logf(s);
                #pragma unroll
                for (int j = 0; j < 4; j++) { rowv[j4][j] = lv[j]; rowc[j4][j] = lc[j]; }
            }
            __syncthreads();
            if (tid == 0) {
                float oc[4]; int of[4];
                for (int k = 0; k < 4; k++) { oc[k] = cum[b * 4 + k]; of[k] = fin[b * 4 + k]; }
                float cv[16]; int ci[16];
                const int fillv[3] = {0, 1, 3};
                for (int k = 0; k < 4; k++) {
                    if (of[k]) {
                        cv[k * 4 + 0] = oc[k];
                        ci[k * 4 + 0] = k * 32000 + EOS_ID;
                        for (int j = 1; j < 4; j++) {
                            cv[k * 4 + j] = oc[k] + NEGV;
                            ci[k * 4 + j] = k * 32000 + fillv[j - 1];
                        }
                    } else {
                        const float lse = rowlse[k];
                        for (int j = 0; j < 4; j++) {
                            cv[k * 4 + j] = oc[k] + (rowv[k][j] - lse);
                            ci[k * 4 + j] = k * 32000 + rowc[k][j];
                        }
                    }
                }
                for (int rr = 0; rr < 4; rr++) {
                    float bvv = -INFINITY; int bix = 0x7FFFFFFF, bp_ = -1;
                    for (int q = 0; q < 16; q++) {
                        if (cv[q] > bvv || (cv[q] == bvv && ci[q] < bix)) {
                            bvv = cv[q]; bix = ci[q]; bp_ = q;
                        }
                    }
                    cv[bp_] = -INFINITY; ci[bp_] = 0x7FFFFFFF;
                    const int k = bix / 32000, v = bix - k * 32000;
                    par[b * 4 + rr] = k;
                    parents[t * 128 + b * 4 + rr] = k;
                    toks[t * 128 + b * 4 + rr] = v;
                    cum[b * 4 + rr] = bvv;
                    tok[b * 4 + rr] = v;
                    fin[b * 4 + rr] = (of[k] || v == EOS_ID) ? 1 : 0;
                }
            }
        }
        gbar(cnt, sense, &ls);
    }

    // ---- backtrack (gather_tree) ----
    if (bid == 0 && tid < 128) {
        const int b = tid >> 2, kc = tid & 3;
        int ptr = kc;
        for (int t = 47; t >= 0; --t) {
            out[b * 192 + t * 4 + kc] = toks[t * 128 + b * 4 + ptr];
            ptr = parents[t * 128 + b * 4 + ptr];
        }
    }
}

// ---------------------------------------------------------------------------
extern "C" void kernel_launch(void* const* d_in, const int* in_sizes, int n_in,
                              void* d_out, int out_size, void* d_ws, size_t ws_size,
                              hipStream_t stream)
{
    (void)in_sizes; (void)n_in; (void)out_size; (void)ws_size;
    const int* enc_in = (const int*)d_in[0];
    const float* dec_emb = (const float*)d_in[3];
    const float* enc_emb = (const float*)d_in[2];
    const float* W_enc = (const float*)d_in[4];
    const float* U_enc = (const float*)d_in[5];
    const float* b_enc = (const float*)d_in[6];
    const float* W_dec = (const float*)d_in[7];
    const float* U_dec = (const float*)d_in[8];
    const float* b_dec = (const float*)d_in[9];
    const float* W_mem = (const float*)d_in[10];
    const float* W_attn = (const float*)d_in[11];
    const float* W_out = (const float*)d_in[12];
    const float* b_out = (const float*)d_in[13];
    int* out = (int*)d_out;

    char* ws = (char*)d_ws;
    size_t off = 0;
    auto alloc = [&](size_t bytes) -> char* {
        char* p = ws + off;
        off = (off + bytes + 255) & ~(size_t)255;
        return p;
    };
    float* Xz      = (float*)alloc(128ull * 32 * 2048 * 4);
    float* Wpe     = (float*)alloc(512ull * 2048 * 4);
    float* Upe     = (float*)alloc(512ull * 2048 * 4);
    float* bpe     = (float*)alloc(2048 * 4);
    float* Bpd     = (float*)alloc(1536ull * 2048 * 4);
    float* bpd     = (float*)alloc(2048 * 4);
    float* enc_out = (float*)alloc(32ull * 128 * 512 * 4);
    float* keysT   = (float*)alloc(32ull * 512 * 128 * 4);
    float* enc_c   = (float*)alloc(32ull * 512 * 4);
    float* AcatA   = (float*)alloc(128ull * 1024 * 4);
    float* AcatB   = (float*)alloc(128ull * 1024 * 4);
    float* cA      = (float*)alloc(128ull * 512 * 4);
    float* cB      = (float*)alloc(128ull * 512 * 4);
    float* atA     = (float*)alloc(128ull * 512 * 4);
    float* atB     = (float*)alloc(128ull * 512 * 4);
    float* pmax    = (float*)alloc(128ull * 512 * 4);
    float* psum    = (float*)alloc(128ull * 512 * 4);
    float* pval    = (float*)alloc(512ull * 512 * 4);
    int*   pcol    = (int*)alloc(512ull * 512 * 4);
    float* cum     = (float*)alloc(128 * 4);
    int* fin       = (int*)alloc(128 * 4);
    int* tok       = (int*)alloc(128 * 4);
    int* par       = (int*)alloc(128 * 4);
    int* parents   = (int*)alloc(48 * 128 * 4);
    int* toks      = (int*)alloc(48 * 128 * 4);
    int* cnt       = (int*)alloc(4);
    int* sense     = (int*)alloc(4);

    // 1. pack weights + zero barrier state
    prep_k<<<16384, 256, 0, stream>>>(W_enc, U_enc, b_enc, W_dec, U_dec, b_dec,
                                      Wpe, bpe, Upe, Bpd, bpd, cnt, sense);
    // 2. Xz = embed(enc_in) @ Wpe + bpe   (packed cols, rows r = s*32+b)
    gemm_k<64, 64, 16, 2, 0><<<dim3(32, 64), 256, 0, stream>>>(
        enc_emb, Wpe, bpe, Xz, 4096, 2048, 512, enc_in);
    // 3. encoder recurrence (one launch)
    encoder_k<<<32, 512, 0, stream>>>(Xz, Upe, enc_out, enc_c);
    // 4. keysT = (enc_out @ W_mem)^T per batch
    gemm_k<64, 64, 16, 0, 1><<<dim3(8, 64), 256, 0, stream>>>(
        enc_out, W_mem, nullptr, keysT, 4096, 512, 512, nullptr);
    // 5. decoder megakernel (init + 48 steps + backtrack)
    mega_k<<<NBLK, 256, 0, stream>>>(
        dec_emb, Bpd, bpd, keysT, enc_out, enc_c, W_attn, W_out, b_out,
        AcatA, AcatB, cA, cB, atA, atB, pmax, psum, pval, pcol,
        cum, fin, tok, par, parents, toks, out, cnt, sense);
}